// Round 7
// baseline (219.783 us; speedup 1.0000x reference)
//
#include <hip/hip_runtime.h>
#include <hip/hip_bf16.h>
#include <hip/hip_fp16.h>
#include <math.h>

// Problem constants (B,S,H,M) = (8,128,768,128)
#define B_   8
#define S_   128
#define H_   768
#define M_   128
#define P_   8256      // S*(S+1)/2 pairs per batch
#define BP_  66048     // B_ * P_
#define EPSF 1e-12f

typedef unsigned short u16;
typedef unsigned int   u32;
typedef _Float16 h16;
typedef _Float16 ffrag __attribute__((ext_vector_type(8)));   // 8 f16 = 4 VGPR
typedef float    f32x16 __attribute__((ext_vector_type(16))); // 32x32 MFMA acc

// packed f16 fma: one v_pk_fma_f16 for two lanes
__device__ __forceinline__ u32 fuse2(u32 x, u32 g, u32 b) {
    __half2 r = __hfma2(__builtin_bit_cast(__half2, x),
                        __builtin_bit_cast(__half2, g),
                        __builtin_bit_cast(__half2, b));
    return __builtin_bit_cast(u32, r);
}
// tanh(x) = 1 - 2/(e^{2x}+1): exp + rcp + fma, branch/copysign-free,
// correct at +-inf (rcp(inf)=0 -> 1; exp(-inf)=0 -> -1)
__device__ __forceinline__ float fast_tanh(float v) {
    float t = __expf(v + v);
    float r = __builtin_amdgcn_rcpf(t + 1.0f);
    return fmaf(-2.0f, r, 1.0f);
}
// async global->LDS 16B per lane; lds dst must be the wave-uniform base
__device__ __forceinline__ void gl_lds16(const h16* g, h16* l) {
    __builtin_amdgcn_global_load_lds(
        (const __attribute__((address_space(1))) u32*)g,
        (__attribute__((address_space(3))) u32*)l, 16, 0, 0);
}
// 8 f32 -> 8 f16 packed as uint4
__device__ __forceinline__ uint4 cvt8(float4 a, float4 b) {
    h16 v[8];
    v[0] = (h16)a.x; v[1] = (h16)a.y; v[2] = (h16)a.z; v[3] = (h16)a.w;
    v[4] = (h16)b.x; v[5] = (h16)b.y; v[6] = (h16)b.z; v[7] = (h16)b.w;
    return *reinterpret_cast<uint4*>(v);
}

// ============ kernel A: B-prepack + biasc + per-row normalize ============
// v9: wgb/wbb conversion REMOVED (k_cond_gemm now stages f32 directly) and
// condb removed -> prep shrinks 6787 -> 2178 blocks, two workspace
// round-trips eliminated.
// blocks [0,1152):      wpk prepack, BN=384 single-tile layout:
//                       wpk[kt24][ch4][n384][e8] = w_{n>>7}[(kt*32+ch*8+e)*128 + (n&127)]
//                       (24KB contiguous image per kt, exact LDS slot order)
// blocks [1152,1154):   biasc (384 f32)
// blocks [1154,1154+1024): row normalize; xn = (x-mean)/(var+eps)^2
#define WPKB  1152
#define NORM0 1154
__global__ void k_prep(const float* __restrict__ seq,
                       const float* __restrict__ we, const float* __restrict__ wh,
                       const float* __restrict__ wt,
                       const float* __restrict__ be, const float* __restrict__ bh,
                       const float* __restrict__ bt,
                       h16* __restrict__ wpk, float* __restrict__ biasc,
                       h16* __restrict__ xn)
{
    __shared__ float red[4];
    const int bx = blockIdx.x;
    const int t = threadIdx.x;

    if (bx < WPKB) {    // ---- wpk prepack ----
        int i  = bx * 256 + t;                 // [0,294912)
        int e  = i & 7;
        int u  = i >> 3;
        int n  = u % 384;
        int w2 = u / 384;                      // [0,96)
        int ch = w2 & 3;
        int kt = w2 >> 2;
        int h  = kt * 32 + ch * 8 + e;         // global k
        int head = n >> 7, m = n & 127;
        const float* src = (head == 0) ? we : (head == 1 ? wh : wt);
        wpk[i] = (h16)src[h * 128 + m];
        return;
    }
    if (bx < NORM0) {   // ---- biasc ----
        int n = (bx - WPKB) * 256 + t;
        if (n < 384)
            biasc[n] = (n < 128) ? be[n] : (n < 256 ? bh[n - 128] : bt[n - 256]);
        return;
    }
    // ---- normalize ----
    const int row = bx - NORM0;
    const int lane = t & 63, wid = t >> 6;
    const float* x = seq + (size_t)row * H_;
    float x0 = x[t], x1 = x[t + 256], x2 = x[t + 512];

    float s = x0 + x1 + x2;
    for (int o = 32; o; o >>= 1) s += __shfl_xor(s, o);
    if (lane == 0) red[wid] = s;
    __syncthreads();
    float mean = (red[0] + red[1] + red[2] + red[3]) * (1.0f / 768.0f);

    float c0 = x0 - mean, c1 = x1 - mean, c2 = x2 - mean;
    float ss = c0 * c0 + c1 * c1 + c2 * c2;
    for (int o = 32; o; o >>= 1) ss += __shfl_xor(ss, o);
    __syncthreads();
    if (lane == 0) red[wid] = ss;
    __syncthreads();
    float var = (red[0] + red[1] + red[2] + red[3]) * (1.0f / 768.0f);
    float sd = var + EPSF;
    float scale = 1.0f / (sd * sd);

    h16* xr = xn + (size_t)row * H_;
    xr[t] = (h16)(c0 * scale); xr[t + 256] = (h16)(c1 * scale); xr[t + 512] = (h16)(c2 * scale);
}

// ============ kernel B: cond GEMM -> gamma_c / beta_c (f16) ============
// C[p][o] = sum_h seq[p,h] * W[o][h] + bias[o];  tiles 64x32, BK=64
// v3: stages DIRECTLY from f32 seq / w_gamma / w_beta with in-flight
// f32->f16 cvt (removes the wgb/wbb/condb convert pass + round-trips).
// grid (16,48): by<24 -> gamma cols by*32 ; else beta cols (by-24)*32
// LDS stride 72 h16 = 144 B (conflict-free as before).
__global__ __launch_bounds__(256) void k_cond_gemm(
    const float* __restrict__ Seq, const float* __restrict__ Wg, const float* __restrict__ Wb,
    const float* __restrict__ gamma, const float* __restrict__ beta,
    h16* __restrict__ Gc, h16* __restrict__ Bc)
{
    __shared__ h16 Ash[64 * 72];
    __shared__ h16 Bsh[32 * 72];
    const int t = threadIdx.x;
    const int row0 = blockIdx.x * 64;
    const int by = blockIdx.y;
    const bool isg = (by < 24);
    const int nc0 = (isg ? by : by - 24) * 32;
    const float* wsrc = isg ? Wg : Wb;

    // A stage: 64 rows x 64 k f32, thread r=t>>2 covers 16 floats at q*16
    const int r = t >> 2, q = t & 3;
    const float* ap = Seq + (size_t)(row0 + r) * H_ + q * 16;
    h16* asto = &Ash[r * 72 + q * 16];
    // B stage: 32 rows x 64 k f32, thread rb=t>>3 covers 8 floats at qb*8
    const int rb = t >> 3, qb = t & 7;
    const float* wp = wsrc + (size_t)(nc0 + rb) * H_ + qb * 8;
    h16* bsto = &Bsh[rb * 72 + qb * 8];

    const int lane = t & 63, wid = t >> 6;
    const int wm0 = (wid >> 1) * 32, wn0 = (wid & 1) * 16;
    const int l15 = lane & 15, quad = lane >> 4, q8 = quad * 8;

    typedef float f32x4 __attribute__((ext_vector_type(4)));
    f32x4 acc[2] = {};
    for (int kt = 0; kt < 12; ++kt) {
        const int k0 = kt * 64;
        float4 a0 = *(const float4*)(ap + k0);      float4 a1 = *(const float4*)(ap + k0 + 4);
        float4 a2 = *(const float4*)(ap + k0 + 8);  float4 a3 = *(const float4*)(ap + k0 + 12);
        float4 w0 = *(const float4*)(wp + k0);      float4 w1 = *(const float4*)(wp + k0 + 4);
        *(uint4*)asto = cvt8(a0, a1); *(uint4*)(asto + 8) = cvt8(a2, a3);
        *(uint4*)bsto = cvt8(w0, w1);
        __syncthreads();
#pragma unroll
        for (int ks = 0; ks < 64; ks += 32) {
            ffrag af[2], bf;
#pragma unroll
            for (int mi = 0; mi < 2; ++mi)
                af[mi] = *reinterpret_cast<const ffrag*>(&Ash[(wm0 + mi * 16 + l15) * 72 + ks + q8]);
            bf = *reinterpret_cast<const ffrag*>(&Bsh[(wn0 + l15) * 72 + ks + q8]);
#pragma unroll
            for (int mi = 0; mi < 2; ++mi)
                acc[mi] = __builtin_amdgcn_mfma_f32_16x16x32_f16(af[mi], bf, acc[mi], 0, 0, 0);
        }
        __syncthreads();
    }

    const float* bias = isg ? gamma : beta;
    h16* outp = isg ? Gc : Bc;
#pragma unroll
    for (int mi = 0; mi < 2; ++mi) {
        int c = wn0 + l15;
        float bv = bias[nc0 + c];
#pragma unroll
        for (int reg = 0; reg < 4; ++reg) {
            int rg = wm0 + mi * 16 + quad * 4 + reg;   // C/D: col=lane&15, row=quad*4+reg (m89)
            outp[(size_t)(row0 + rg) * H_ + nc0 + c] = (h16)(acc[mi][reg] + bv);
        }
    }
}

// ============ kernel C: fused pair GEMM ============
// out[head, gp, m] = tanh( (xn[b,j]*gc[b,i] + bc[b,i]) @ W[:, cg] + biasc[cg] )
// v9: 128 x 384 block tile (ALL col-blocks merged), BK=32, 512 threads,
// 8 waves 2x4 (wave tile 64x96, acc 2x3 f32x16 = 96 VGPR).
// r6 post-mortem: occupancy 17/29/47% all flat -> throughput-bound on L2->CU
// bytes (~1.5 GB per dispatch ~ 19 TB/s ~ 55% of L2 ceiling).  BN=384 reads
// each fused-A row ONCE (was 3x) and halves B bytes/FLOP: loop traffic
// 1.5 GB -> ~0.6 GB.  LDS 64 KB -> 1 block/CU (grid 516 = 2.016 gens;
// integer tail accepted -- occupancy proven not to matter).
// LDS chunk-major slot(ch,row)=(ch*ROWS+row)*8; prepacked-B DMA (3x 8KB
// rounds, fully coalesced); plain syncthreads dbuf (r4 proved fancy
// pipelining doesn't help).
__global__ __launch_bounds__(512, 2) void k_pair_gemm(
    const h16* __restrict__ Xn, const h16* __restrict__ Gcb, const h16* __restrict__ Bcb,
    const h16* __restrict__ Wpk, const float* __restrict__ biasc,
    float* __restrict__ out)
{
    __shared__ h16 Ash[2][4 * 128 * 8];   // 8 KB per buf
    __shared__ h16 Bsh[2][4 * 384 * 8];   // 24 KB per buf

    const int t = threadIdx.x;
    const int row0 = blockIdx.x * 128;

    // ---- per-thread staging-row decode (row r_s, k-octet q) ----
    const int r_s = t >> 2, q = t & 3;
    int gp = row0 + r_s;
    int b = gp / P_;
    int p = gp - b * P_;
    int i = (int)((257.0f - sqrtf(66049.0f - 8.0f * (float)p)) * 0.5f);
    if (i < 0) i = 0; if (i > 127) i = 127;
    while (i > 0 && (i * (257 - i)) / 2 > p) --i;
    while (((i + 1) * (256 - i)) / 2 <= p) ++i;
    int j = i + (p - (i * (257 - i)) / 2);

    const h16* xp  = Xn  + (size_t)(b * 128 + j) * H_ + q * 8;
    const h16* gp_ = Gcb + (size_t)(b * 128 + i) * H_ + q * 8;
    const h16* bp_ = Bcb + (size_t)(b * 128 + i) * H_ + q * 8;
    const int aw = (q * 128 + r_s) * 8;

    // B DMA: prepacked tile for kt is 12288 h16 (24KB) contiguous, slot order
    const int wud = t & ~63;              // wave-uniform slot base

    const int lane = t & 63, wid = t >> 6;
    const int wm0 = (wid >> 2) * 64, wn0 = (wid & 3) * 96;
    const int l31 = lane & 31, hi = lane >> 5;

    // ---------- prologue: stage kt=0 into buffer 0 ----------
#pragma unroll
    for (int c = 0; c < 3; ++c)
        gl_lds16(Wpk + (size_t)(c * 512 + t) * 8, &Bsh[0][(c * 512 + wud) * 8]);
    {
        uint4 xa = *(const uint4*)xp;
        uint4 ga = *(const uint4*)gp_;
        uint4 ba = *(const uint4*)bp_;
        uint4 f;
        f.x = fuse2(xa.x, ga.x, ba.x); f.y = fuse2(xa.y, ga.y, ba.y);
        f.z = fuse2(xa.z, ga.z, ba.z); f.w = fuse2(xa.w, ga.w, ba.w);
        *(uint4*)&Ash[0][aw] = f;
    }
    __syncthreads();

    f32x16 acc[2][3] = {};
#pragma unroll 2
    for (int kt = 0; kt < 24; ++kt) {
        const int buf = kt & 1, nbf = buf ^ 1;
        uint4 xa, ga, ba;
        if (kt < 23) {
            // next-B DMA first (longest latency), then next-A loads
            const h16* wnext = Wpk + (size_t)(kt + 1) * 12288;
#pragma unroll
            for (int c = 0; c < 3; ++c)
                gl_lds16(wnext + (size_t)(c * 512 + t) * 8, &Bsh[nbf][(c * 512 + wud) * 8]);
            const int k0 = (kt + 1) * 32;
            xa = *(const uint4*)(xp + k0);
            ga = *(const uint4*)(gp_ + k0);
            ba = *(const uint4*)(bp_ + k0);
        }

#pragma unroll
        for (int ks = 0; ks < 2; ++ks) {
            const int ch0 = ks * 2;           // k-window ks*16 -> octets ch0, ch0+1
            ffrag af[2], bf[3];
#pragma unroll
            for (int mi = 0; mi < 2; ++mi)
                af[mi] = *reinterpret_cast<const ffrag*>(
                    &Ash[buf][((ch0 + hi) * 128 + wm0 + mi * 32 + l31) * 8]);
#pragma unroll
            for (int ni = 0; ni < 3; ++ni)
                bf[ni] = *reinterpret_cast<const ffrag*>(
                    &Bsh[buf][((ch0 + hi) * 384 + wn0 + ni * 32 + l31) * 8]);
#pragma unroll
            for (int mi = 0; mi < 2; ++mi)
#pragma unroll
                for (int ni = 0; ni < 3; ++ni)
                    acc[mi][ni] = __builtin_amdgcn_mfma_f32_32x32x16_f16(af[mi], bf[ni], acc[mi][ni], 0, 0, 0);
        }

        if (kt < 23) {
            uint4 f;
            f.x = fuse2(xa.x, ga.x, ba.x); f.y = fuse2(xa.y, ga.y, ba.y);
            f.z = fuse2(xa.z, ga.z, ba.z); f.w = fuse2(xa.w, ga.w, ba.w);
            *(uint4*)&Ash[nbf][aw] = f;
        }
        __syncthreads();
    }

    // epilogue: bias + tanh + store
    // C/D 32x32: col = lane&31, row = (reg&3) + 8*(reg>>2) + 4*(lane>>5)  [m74/m101]
    // col groups are 32-aligned -> head uniform per store instr
#pragma unroll
    for (int mi = 0; mi < 2; ++mi)
#pragma unroll
        for (int ni = 0; ni < 3; ++ni) {
            int c = wn0 + ni * 32 + l31;      // [0,384)
            int head = c >> 7, m = c & 127;
            float bv = biasc[c];
#pragma unroll
            for (int reg = 0; reg < 16; ++reg) {
                int rg = wm0 + mi * 32 + (reg & 3) + 8 * (reg >> 2) + 4 * hi;
                out[((size_t)head * BP_ + row0 + rg) * M_ + m] = fast_tanh(acc[mi][ni][reg] + bv);
            }
        }
}

extern "C" void kernel_launch(void* const* d_in, const int* in_sizes, int n_in,
                              void* d_out, int out_size, void* d_ws, size_t ws_size,
                              hipStream_t stream)
{
    const float* seq     = (const float*)d_in[0];
    const float* gamma   = (const float*)d_in[1];
    const float* beta    = (const float*)d_in[2];
    const float* w_beta  = (const float*)d_in[3];
    const float* w_gamma = (const float*)d_in[4];
    const float* w_ent   = (const float*)d_in[5];
    const float* b_ent   = (const float*)d_in[6];
    const float* w_head  = (const float*)d_in[7];
    const float* b_head  = (const float*)d_in[8];
    const float* w_tail  = (const float*)d_in[9];
    const float* b_tail  = (const float*)d_in[10];
    float* out = (float*)d_out;

    // workspace layout (all 16B-aligned)
    char* ws = (char*)d_ws;
    h16* xn    = (h16*)ws; ws += (size_t)1024 * 768 * 2;  // normalized rows, f16
    h16* wpk   = (h16*)ws; ws += (size_t)294912 * 2;      // pre-packed B tiles (24 x 24KB)
    h16* gc    = (h16*)ws; ws += (size_t)1024 * 768 * 2;  // gamma_c f16
    h16* bc    = (h16*)ws; ws += (size_t)1024 * 768 * 2;  // beta_c  f16
    float* biasc = (float*)ws; ws += 384 * 4;             // [ent|head|tail] bias

    hipLaunchKernelGGL(k_prep, dim3(NORM0 + 1024), dim3(256), 0, stream,
                       seq, w_ent, w_head, w_tail,
                       b_ent, b_head, b_tail, wpk, biasc, xn);
    hipLaunchKernelGGL(k_cond_gemm, dim3(16, 48), dim3(256), 0, stream,
                       seq, w_gamma, w_beta, gamma, beta, gc, bc);
    hipLaunchKernelGGL(k_pair_gemm, dim3(516), dim3(512), 0, stream,
                       xn, gc, bc, wpk, biasc, out);
}

// Round 8
// 203.138 us; speedup vs baseline: 1.0819x; 1.0819x over previous
//
#include <hip/hip_runtime.h>
#include <hip/hip_bf16.h>
#include <hip/hip_fp16.h>
#include <math.h>

// Problem constants (B,S,H,M) = (8,128,768,128)
#define B_   8
#define S_   128
#define H_   768
#define M_   128
#define P_   8256      // S*(S+1)/2 pairs per batch
#define BP_  66048     // B_ * P_
#define EPSF 1e-12f

typedef unsigned short u16;
typedef unsigned int   u32;
typedef _Float16 h16;
typedef _Float16 ffrag __attribute__((ext_vector_type(8)));   // 8 f16 = 4 VGPR
typedef float    f32x16 __attribute__((ext_vector_type(16))); // 32x32 MFMA acc

// packed f16 fma: one v_pk_fma_f16 for two lanes
__device__ __forceinline__ u32 fuse2(u32 x, u32 g, u32 b) {
    __half2 r = __hfma2(__builtin_bit_cast(__half2, x),
                        __builtin_bit_cast(__half2, g),
                        __builtin_bit_cast(__half2, b));
    return __builtin_bit_cast(u32, r);
}
// tanh(x) = 1 - 2/(e^{2x}+1): exp + rcp + fma, branch/copysign-free,
// correct at +-inf (rcp(inf)=0 -> 1; exp(-inf)=0 -> -1)
__device__ __forceinline__ float fast_tanh(float v) {
    float t = __expf(v + v);
    float r = __builtin_amdgcn_rcpf(t + 1.0f);
    return fmaf(-2.0f, r, 1.0f);
}
// async global->LDS 16B per lane; lds dst must be the wave-uniform base
__device__ __forceinline__ void gl_lds16(const h16* g, h16* l) {
    __builtin_amdgcn_global_load_lds(
        (const __attribute__((address_space(1))) u32*)g,
        (__attribute__((address_space(3))) u32*)l, 16, 0, 0);
}
// 8 f32 -> 8 f16 packed as uint4
__device__ __forceinline__ uint4 cvt8(float4 a, float4 b) {
    h16 v[8];
    v[0] = (h16)a.x; v[1] = (h16)a.y; v[2] = (h16)a.z; v[3] = (h16)a.w;
    v[4] = (h16)b.x; v[5] = (h16)b.y; v[6] = (h16)b.z; v[7] = (h16)b.w;
    return *reinterpret_cast<uint4*>(v);
}

// ============ kernel PRE: cond GEMM + wpk prepack + biasc + normalize ============
// r7 post-mortem: total - pair ~= 120 us every round (60% of wall clock!) --
// three SERIALIZED dispatches of latency-bound work.  prep and cond are
// data-independent (cond reads only inputs), so: ONE dispatch, disjoint
// block ranges, concurrent execution.
//   [0,768):     cond GEMM (f32-staged, 64x32 tiles, BK=64) -> gc/bc
//   [768,792):   wpk prepack via LDS-staged transpose, 1 block per kt:
//                stage 3x32x128 f32 coalesced -> LDS (48 KB), emit
//                wpk[nb][kt][ch][n128][e8] as coalesced uint4 stores.
//                (replaces the old 512B-stride gather: 64 lines/wave)
//   [792,794):   biasc (384 f32)
//   [794,1818):  row normalize; xn = (x-mean)/(var+eps)^2
#define CONDB 768
#define WPK0  768
#define BIAS0 792
#define NORM0 794
__global__ __launch_bounds__(256) void k_pre(
    const float* __restrict__ seq,
    const float* __restrict__ wg, const float* __restrict__ wb,
    const float* __restrict__ we, const float* __restrict__ wh,
    const float* __restrict__ wt,
    const float* __restrict__ gamma, const float* __restrict__ beta,
    const float* __restrict__ be, const float* __restrict__ bh,
    const float* __restrict__ bt,
    h16* __restrict__ wpk, float* __restrict__ biasc,
    h16* __restrict__ xn, h16* __restrict__ Gc, h16* __restrict__ Bc)
{
    __shared__ __align__(16) char smem[49152];   // union: cond 13.8KB | wpk 48KB | norm 16B
    const int bx = blockIdx.x;
    const int t = threadIdx.x;

    if (bx < CONDB) {   // ================= cond GEMM =================
        h16* Ash = (h16*)smem;                 // [64*72]
        h16* Bsh = (h16*)smem + 64 * 72;       // [32*72]
        const int rbx = bx & 15, by = bx >> 4;
        const int row0 = rbx * 64;
        const bool isg = (by < 24);
        const int nc0 = (isg ? by : by - 24) * 32;
        const float* wsrc = isg ? wg : wb;

        // A stage: 64 rows x 64 k f32, thread r=t>>2 covers 16 floats at q*16
        const int r = t >> 2, q = t & 3;
        const float* ap = seq + (size_t)(row0 + r) * H_ + q * 16;
        h16* asto = &Ash[r * 72 + q * 16];
        // B stage: 32 rows x 64 k f32, thread rb=t>>3 covers 8 floats at qb*8
        const int rb = t >> 3, qb = t & 7;
        const float* wp = wsrc + (size_t)(nc0 + rb) * H_ + qb * 8;
        h16* bsto = &Bsh[rb * 72 + qb * 8];

        const int lane = t & 63, wid = t >> 6;
        const int wm0 = (wid >> 1) * 32, wn0 = (wid & 1) * 16;
        const int l15 = lane & 15, quad = lane >> 4, q8 = quad * 8;

        typedef float f32x4 __attribute__((ext_vector_type(4)));
        f32x4 acc[2] = {};
        for (int kt = 0; kt < 12; ++kt) {
            const int k0 = kt * 64;
            float4 a0 = *(const float4*)(ap + k0);      float4 a1 = *(const float4*)(ap + k0 + 4);
            float4 a2 = *(const float4*)(ap + k0 + 8);  float4 a3 = *(const float4*)(ap + k0 + 12);
            float4 w0 = *(const float4*)(wp + k0);      float4 w1 = *(const float4*)(wp + k0 + 4);
            *(uint4*)asto = cvt8(a0, a1); *(uint4*)(asto + 8) = cvt8(a2, a3);
            *(uint4*)bsto = cvt8(w0, w1);
            __syncthreads();
#pragma unroll
            for (int ks = 0; ks < 64; ks += 32) {
                ffrag af[2], bf;
#pragma unroll
                for (int mi = 0; mi < 2; ++mi)
                    af[mi] = *reinterpret_cast<const ffrag*>(&Ash[(wm0 + mi * 16 + l15) * 72 + ks + q8]);
                bf = *reinterpret_cast<const ffrag*>(&Bsh[(wn0 + l15) * 72 + ks + q8]);
#pragma unroll
                for (int mi = 0; mi < 2; ++mi)
                    acc[mi] = __builtin_amdgcn_mfma_f32_16x16x32_f16(af[mi], bf, acc[mi], 0, 0, 0);
            }
            __syncthreads();
        }

        const float* bias = isg ? gamma : beta;
        h16* outp = isg ? Gc : Bc;
#pragma unroll
        for (int mi = 0; mi < 2; ++mi) {
            int c = wn0 + l15;
            float bv = bias[nc0 + c];
#pragma unroll
            for (int reg = 0; reg < 4; ++reg) {
                int rg = wm0 + mi * 16 + quad * 4 + reg;   // C/D: col=lane&15, row=quad*4+reg (m89)
                outp[(size_t)(row0 + rg) * H_ + nc0 + c] = (h16)(acc[mi][reg] + bv);
            }
        }
        return;
    }

    if (bx < BIAS0) {   // ================= wpk prepack (1 block per kt) =================
        const int kt = bx - WPK0;
        float* stage = (float*)smem;           // [3][32][128] f32 = 48 KB
        // stage: coalesced float4 reads from the 3 weight mats, rows kt*32..+31
        int f = t;                             // float4 granule index [0,3072)
#pragma unroll
        for (int k = 0; k < 12; ++k, f += 256) {
            int head = f >> 10, rem = f & 1023;
            int h = rem >> 5, m4 = rem & 31;
            const float* src = (head == 0) ? we : (head == 1 ? wh : wt);
            *(float4*)(stage + (size_t)f * 4) =
                *(const float4*)(src + (size_t)(kt * 32 + h) * 128 + m4 * 4);
        }
        __syncthreads();
        // emit: wpk[nb][kt][ch][nl][e]; slot s = nb*512 + ch*128 + nl, coalesced uint4
#pragma unroll
        for (int rr = 0; rr < 6; ++rr) {
            int s = t + 256 * rr;              // [0,1536)
            int nb = s >> 9, rem = s & 511;
            int ch = rem >> 7, nl = rem & 127;
            h16 v[8];
#pragma unroll
            for (int e = 0; e < 8; ++e)
                v[e] = (h16)stage[(size_t)((nb * 32 + ch * 8 + e) * 128 + nl)];
            *(uint4*)(wpk + (size_t)nb * 98304 + kt * 4096 + (ch * 128 + nl) * 8) = *(uint4*)v;
        }
        return;
    }

    if (bx < NORM0) {   // ================= biasc =================
        int n = (bx - BIAS0) * 256 + t;
        if (n < 384)
            biasc[n] = (n < 128) ? be[n] : (n < 256 ? bh[n - 128] : bt[n - 256]);
        return;
    }

    // ================= normalize =================
    float* red = (float*)smem;
    const int row = bx - NORM0;
    const int lane = t & 63, wid = t >> 6;
    const float* x = seq + (size_t)row * H_;
    float x0 = x[t], x1 = x[t + 256], x2 = x[t + 512];

    float s = x0 + x1 + x2;
    for (int o = 32; o; o >>= 1) s += __shfl_xor(s, o);
    if (lane == 0) red[wid] = s;
    __syncthreads();
    float mean = (red[0] + red[1] + red[2] + red[3]) * (1.0f / 768.0f);

    float c0 = x0 - mean, c1 = x1 - mean, c2 = x2 - mean;
    float ss = c0 * c0 + c1 * c1 + c2 * c2;
    for (int o = 32; o; o >>= 1) ss += __shfl_xor(ss, o);
    __syncthreads();
    if (lane == 0) red[wid] = ss;
    __syncthreads();
    float var = (red[0] + red[1] + red[2] + red[3]) * (1.0f / 768.0f);
    float sd = var + EPSF;
    float scale = 1.0f / (sd * sd);

    h16* xr = xn + (size_t)row * H_;
    xr[t] = (h16)(c0 * scale); xr[t + 256] = (h16)(c1 * scale); xr[t + 512] = (h16)(c2 * scale);
}

// ============ kernel C: fused pair GEMM (r6 v8, verified 80.6 us — unchanged) ============
// out[head, gp, m] = tanh( (xn[b,j]*gc[b,i] + bc[b,i]) @ W[:, cg] + biasc[cg] )
// 64x128 block tile, BK=32, 32x32x16 MFMA, 6 blocks/CU, grid (3,1032).
__global__ __launch_bounds__(256, 6) void k_pair_gemm(
    const h16* __restrict__ Xn, const h16* __restrict__ Gcb, const h16* __restrict__ Bcb,
    const h16* __restrict__ Wpk, const float* __restrict__ biasc,
    float* __restrict__ out)
{
    __shared__ h16 Ash[2][4 * 64 * 8];    // 4 KB per buf
    __shared__ h16 Bsh[2][4 * 128 * 8];   // 8 KB per buf

    const int t = threadIdx.x;
    const int nb = blockIdx.x;            // 0..2 -> cols nb*128 (fast dim)
    const int row0 = blockIdx.y * 64;

    // ---- per-thread staging-row decode (row r_s, k-octet c4) ----
    const int r_s = t >> 2, c4 = t & 3;
    int gp = row0 + r_s;
    int b = gp / P_;
    int p = gp - b * P_;
    int i = (int)((257.0f - sqrtf(66049.0f - 8.0f * (float)p)) * 0.5f);
    if (i < 0) i = 0; if (i > 127) i = 127;
    while (i > 0 && (i * (257 - i)) / 2 > p) --i;
    while (((i + 1) * (256 - i)) / 2 <= p) ++i;
    int j = i + (p - (i * (257 - i)) / 2);

    const h16* xp  = Xn  + (size_t)(b * 128 + j) * H_ + c4 * 8;
    const h16* gp_ = Gcb + (size_t)(b * 128 + i) * H_ + c4 * 8;
    const h16* bp_ = Bcb + (size_t)(b * 128 + i) * H_ + c4 * 8;
    const int aw = (c4 * 64 + r_s) * 8;

    // B DMA: prepacked tile for (nb,kt) is 4096 h16 contiguous, slot order
    const h16* wtile = Wpk + (size_t)nb * 24 * 4096;
    const int wud = t & ~63;              // wave-uniform slot base

    const int lane = t & 63, wid = t >> 6;
    const int wm0 = (wid >> 1) * 32, wn0 = (wid & 1) * 64;
    const int l31 = lane & 31, hi = lane >> 5;

    // ---------- prologue: stage kt=0 into buffer 0 ----------
#pragma unroll
    for (int c = 0; c < 2; ++c)
        gl_lds16(wtile + (size_t)(c * 256 + t) * 8, &Bsh[0][(c * 256 + wud) * 8]);
    {
        uint4 xa = *(const uint4*)xp;
        uint4 ga = *(const uint4*)gp_;
        uint4 ba = *(const uint4*)bp_;
        uint4 f;
        f.x = fuse2(xa.x, ga.x, ba.x); f.y = fuse2(xa.y, ga.y, ba.y);
        f.z = fuse2(xa.z, ga.z, ba.z); f.w = fuse2(xa.w, ga.w, ba.w);
        *(uint4*)&Ash[0][aw] = f;
    }
    __syncthreads();

    f32x16 acc[2] = {};
#pragma unroll 2
    for (int kt = 0; kt < 24; ++kt) {
        const int buf = kt & 1, nbf = buf ^ 1;
        uint4 xa, ga, ba;
        if (kt < 23) {
            // next-B DMA first (longest latency), then next-A loads
            const h16* wnext = wtile + (size_t)(kt + 1) * 4096;
#pragma unroll
            for (int c = 0; c < 2; ++c)
                gl_lds16(wnext + (size_t)(c * 256 + t) * 8, &Bsh[nbf][(c * 256 + wud) * 8]);
            const int k0 = (kt + 1) * 32;
            xa = *(const uint4*)(xp + k0);
            ga = *(const uint4*)(gp_ + k0);
            ba = *(const uint4*)(bp_ + k0);
        }

#pragma unroll
        for (int ks = 0; ks < 2; ++ks) {
            const int ch0 = ks * 2;           // k-window ks*16 -> chunks ch0, ch0+1
            ffrag af, bf[2];
            af = *reinterpret_cast<const ffrag*>(
                &Ash[buf][((ch0 + hi) * 64 + wm0 + l31) * 8]);
#pragma unroll
            for (int ni = 0; ni < 2; ++ni)
                bf[ni] = *reinterpret_cast<const ffrag*>(
                    &Bsh[buf][((ch0 + hi) * 128 + wn0 + ni * 32 + l31) * 8]);
#pragma unroll
            for (int ni = 0; ni < 2; ++ni)
                acc[ni] = __builtin_amdgcn_mfma_f32_32x32x16_f16(af, bf[ni], acc[ni], 0, 0, 0);
        }

        if (kt < 23) {
            uint4 f;
            f.x = fuse2(xa.x, ga.x, ba.x); f.y = fuse2(xa.y, ga.y, ba.y);
            f.z = fuse2(xa.z, ga.z, ba.z); f.w = fuse2(xa.w, ga.w, ba.w);
            *(uint4*)&Ash[nbf][aw] = f;
        }
        __syncthreads();
    }

    // epilogue: bias + tanh + store (head == nb, m == col, since BN=128)
    // C/D 32x32: col = lane&31, row = (reg&3) + 8*(reg>>2) + 4*(lane>>5)  [m74/m101]
#pragma unroll
    for (int ni = 0; ni < 2; ++ni) {
        int c = wn0 + ni * 32 + l31;
        float bv = biasc[nb * 128 + c];
#pragma unroll
        for (int reg = 0; reg < 16; ++reg) {
            int rg = wm0 + (reg & 3) + 8 * (reg >> 2) + 4 * hi;
            out[((size_t)nb * BP_ + row0 + rg) * M_ + c] = fast_tanh(acc[ni][reg] + bv);
        }
    }
}

extern "C" void kernel_launch(void* const* d_in, const int* in_sizes, int n_in,
                              void* d_out, int out_size, void* d_ws, size_t ws_size,
                              hipStream_t stream)
{
    const float* seq     = (const float*)d_in[0];
    const float* gamma   = (const float*)d_in[1];
    const float* beta    = (const float*)d_in[2];
    const float* w_beta  = (const float*)d_in[3];
    const float* w_gamma = (const float*)d_in[4];
    const float* w_ent   = (const float*)d_in[5];
    const float* b_ent   = (const float*)d_in[6];
    const float* w_head  = (const float*)d_in[7];
    const float* b_head  = (const float*)d_in[8];
    const float* w_tail  = (const float*)d_in[9];
    const float* b_tail  = (const float*)d_in[10];
    float* out = (float*)d_out;

    // workspace layout (all 16B-aligned)
    char* ws = (char*)d_ws;
    h16* xn    = (h16*)ws; ws += (size_t)1024 * 768 * 2;  // normalized rows, f16
    h16* wpk   = (h16*)ws; ws += (size_t)294912 * 2;      // pre-packed B tiles [nb][kt][ch][128][8]
    h16* gc    = (h16*)ws; ws += (size_t)1024 * 768 * 2;  // gamma_c f16
    h16* bc    = (h16*)ws; ws += (size_t)1024 * 768 * 2;  // beta_c  f16
    float* biasc = (float*)ws; ws += 384 * 4;             // [ent|head|tail] bias

    hipLaunchKernelGGL(k_pre, dim3(NORM0 + 1024), dim3(256), 0, stream,
                       seq, w_gamma, w_beta, w_ent, w_head, w_tail,
                       gamma, beta, b_ent, b_head, b_tail,
                       wpk, biasc, xn, gc, bc);
    hipLaunchKernelGGL(k_pair_gemm, dim3(3, 1032), dim3(256), 0, stream,
                       xn, gc, bc, wpk, biasc, out);
}

// Round 9
// 202.288 us; speedup vs baseline: 1.0865x; 1.0042x over previous
//
#include <hip/hip_runtime.h>
#include <hip/hip_bf16.h>
#include <hip/hip_fp16.h>
#include <math.h>

// Problem constants (B,S,H,M) = (8,128,768,128)
#define B_   8
#define S_   128
#define H_   768
#define M_   128
#define P_   8256      // S*(S+1)/2 pairs per batch
#define BP_  66048     // B_ * P_
#define EPSF 1e-12f

typedef unsigned short u16;
typedef unsigned int   u32;
typedef _Float16 h16;
typedef _Float16 ffrag __attribute__((ext_vector_type(8)));   // 8 f16 = 4 VGPR
typedef float    f32x16 __attribute__((ext_vector_type(16))); // 32x32 MFMA acc

// packed f16 fma: one v_pk_fma_f16 for two lanes
__device__ __forceinline__ u32 fuse2(u32 x, u32 g, u32 b) {
    __half2 r = __hfma2(__builtin_bit_cast(__half2, x),
                        __builtin_bit_cast(__half2, g),
                        __builtin_bit_cast(__half2, b));
    return __builtin_bit_cast(u32, r);
}
// tanh(x) = 1 - 2/(e^{2x}+1): exp + rcp + fma, branch/copysign-free,
// correct at +-inf (rcp(inf)=0 -> 1; exp(-inf)=0 -> -1)
__device__ __forceinline__ float fast_tanh(float v) {
    float t = __expf(v + v);
    float r = __builtin_amdgcn_rcpf(t + 1.0f);
    return fmaf(-2.0f, r, 1.0f);
}
// async global->LDS 16B per lane; lds dst must be the wave-uniform base
__device__ __forceinline__ void gl_lds16(const h16* g, h16* l) {
    __builtin_amdgcn_global_load_lds(
        (const __attribute__((address_space(1))) u32*)g,
        (__attribute__((address_space(3))) u32*)l, 16, 0, 0);
}
// 8 f32 -> 8 f16 packed as uint4
__device__ __forceinline__ uint4 cvt8(float4 a, float4 b) {
    h16 v[8];
    v[0] = (h16)a.x; v[1] = (h16)a.y; v[2] = (h16)a.z; v[3] = (h16)a.w;
    v[4] = (h16)b.x; v[5] = (h16)b.y; v[6] = (h16)b.z; v[7] = (h16)b.w;
    return *reinterpret_cast<uint4*>(v);
}

// ============ kernel PRE: cond GEMM + wpk prepack + biasc + normalize ============
// One dispatch, disjoint block ranges (r8).  v2: smem union shrunk 48->24 KB
// (wpk transpose runs in two 16-row passes) -> 6 blocks/CU for the cond and
// norm branches (was 3, capped by the 48 KB union).
//   [0,768):     cond GEMM (f32-staged, 64x32 tiles, BK=64) -> gc/bc
//   [768,792):   wpk prepack via LDS-staged transpose, 1 block per kt,
//                two passes of [3][16][128] f32 (24 KB)
//   [792,794):   biasc (384 f32)
//   [794,1818):  row normalize; xn = (x-mean)/(var+eps)^2
#define CONDB 768
#define WPK0  768
#define BIAS0 792
#define NORM0 794
__global__ __launch_bounds__(256) void k_pre(
    const float* __restrict__ seq,
    const float* __restrict__ wg, const float* __restrict__ wb,
    const float* __restrict__ we, const float* __restrict__ wh,
    const float* __restrict__ wt,
    const float* __restrict__ gamma, const float* __restrict__ beta,
    const float* __restrict__ be, const float* __restrict__ bh,
    const float* __restrict__ bt,
    h16* __restrict__ wpk, float* __restrict__ biasc,
    h16* __restrict__ xn, h16* __restrict__ Gc, h16* __restrict__ Bc)
{
    __shared__ __align__(16) char smem[24576];   // union: cond 13.8KB | wpk 24KB | norm 16B
    const int bx = blockIdx.x;
    const int t = threadIdx.x;

    if (bx < CONDB) {   // ================= cond GEMM =================
        h16* Ash = (h16*)smem;                 // [64*72]
        h16* Bsh = (h16*)smem + 64 * 72;       // [32*72]
        const int rbx = bx & 15, by = bx >> 4;
        const int row0 = rbx * 64;
        const bool isg = (by < 24);
        const int nc0 = (isg ? by : by - 24) * 32;
        const float* wsrc = isg ? wg : wb;

        // A stage: 64 rows x 64 k f32, thread r=t>>2 covers 16 floats at q*16
        const int r = t >> 2, q = t & 3;
        const float* ap = seq + (size_t)(row0 + r) * H_ + q * 16;
        h16* asto = &Ash[r * 72 + q * 16];
        // B stage: 32 rows x 64 k f32, thread rb=t>>3 covers 8 floats at qb*8
        const int rb = t >> 3, qb = t & 7;
        const float* wp = wsrc + (size_t)(nc0 + rb) * H_ + qb * 8;
        h16* bsto = &Bsh[rb * 72 + qb * 8];

        const int lane = t & 63, wid = t >> 6;
        const int wm0 = (wid >> 1) * 32, wn0 = (wid & 1) * 16;
        const int l15 = lane & 15, quad = lane >> 4, q8 = quad * 8;

        typedef float f32x4 __attribute__((ext_vector_type(4)));
        f32x4 acc[2] = {};
        for (int kt = 0; kt < 12; ++kt) {
            const int k0 = kt * 64;
            float4 a0 = *(const float4*)(ap + k0);      float4 a1 = *(const float4*)(ap + k0 + 4);
            float4 a2 = *(const float4*)(ap + k0 + 8);  float4 a3 = *(const float4*)(ap + k0 + 12);
            float4 w0 = *(const float4*)(wp + k0);      float4 w1 = *(const float4*)(wp + k0 + 4);
            *(uint4*)asto = cvt8(a0, a1); *(uint4*)(asto + 8) = cvt8(a2, a3);
            *(uint4*)bsto = cvt8(w0, w1);
            __syncthreads();
#pragma unroll
            for (int ks = 0; ks < 64; ks += 32) {
                ffrag af[2], bf;
#pragma unroll
                for (int mi = 0; mi < 2; ++mi)
                    af[mi] = *reinterpret_cast<const ffrag*>(&Ash[(wm0 + mi * 16 + l15) * 72 + ks + q8]);
                bf = *reinterpret_cast<const ffrag*>(&Bsh[(wn0 + l15) * 72 + ks + q8]);
#pragma unroll
                for (int mi = 0; mi < 2; ++mi)
                    acc[mi] = __builtin_amdgcn_mfma_f32_16x16x32_f16(af[mi], bf, acc[mi], 0, 0, 0);
            }
            __syncthreads();
        }

        const float* bias = isg ? gamma : beta;
        h16* outp = isg ? Gc : Bc;
#pragma unroll
        for (int mi = 0; mi < 2; ++mi) {
            int c = wn0 + l15;
            float bv = bias[nc0 + c];
#pragma unroll
            for (int reg = 0; reg < 4; ++reg) {
                int rg = wm0 + mi * 16 + quad * 4 + reg;   // C/D: col=lane&15, row=quad*4+reg (m89)
                outp[(size_t)(row0 + rg) * H_ + nc0 + c] = (h16)(acc[mi][reg] + bv);
            }
        }
        return;
    }

    if (bx < BIAS0) {   // ================= wpk prepack (1 block per kt, 2 passes) =================
        const int kt = bx - WPK0;
        float* stage = (float*)smem;           // [3][16][128] f32 = 24 KB
#pragma unroll
        for (int pass = 0; pass < 2; ++pass) {
            if (pass) __syncthreads();         // protect stage overwrite
            // stage: coalesced float4 reads, k-rows kt*32+pass*16 .. +16
            int f = t;                         // float4 granule index [0,1536)
#pragma unroll
            for (int k = 0; k < 6; ++k, f += 256) {
                int head = f >> 9, rem = f & 511;
                int r = rem >> 5, m4 = rem & 31;
                const float* src = (head == 0) ? we : (head == 1 ? wh : wt);
                *(float4*)(stage + (size_t)(head * 16 + r) * 128 + m4 * 4) =
                    *(const float4*)(src + (size_t)(kt * 32 + pass * 16 + r) * 128 + m4 * 4);
            }
            __syncthreads();
            // emit: wpk[nb][kt][ch][nl][e], ch = pass*2 + chl; coalesced uint4
#pragma unroll
            for (int e2 = 0; e2 < 3; ++e2) {
                int s = t + 256 * e2;          // [0,768)
                int nbw = s >> 8, rem = s & 255;
                int chl = rem >> 7, nl = rem & 127;
                h16 v[8];
#pragma unroll
                for (int e = 0; e < 8; ++e)
                    v[e] = (h16)stage[(size_t)(nbw * 16 + chl * 8 + e) * 128 + nl];
                *(uint4*)(wpk + (size_t)nbw * 98304 + kt * 4096 +
                          ((pass * 2 + chl) * 128 + nl) * 8) = *(uint4*)v;
            }
            f = t;  // silence unused warnings
        }
        return;
    }

    if (bx < NORM0) {   // ================= biasc =================
        int n = (bx - BIAS0) * 256 + t;
        if (n < 384)
            biasc[n] = (n < 128) ? be[n] : (n < 256 ? bh[n - 128] : bt[n - 256]);
        return;
    }

    // ================= normalize =================
    float* red = (float*)smem;
    const int row = bx - NORM0;
    const int lane = t & 63, wid = t >> 6;
    const float* x = seq + (size_t)row * H_;
    float x0 = x[t], x1 = x[t + 256], x2 = x[t + 512];

    float s = x0 + x1 + x2;
    for (int o = 32; o; o >>= 1) s += __shfl_xor(s, o);
    if (lane == 0) red[wid] = s;
    __syncthreads();
    float mean = (red[0] + red[1] + red[2] + red[3]) * (1.0f / 768.0f);

    float c0 = x0 - mean, c1 = x1 - mean, c2 = x2 - mean;
    float ss = c0 * c0 + c1 * c1 + c2 * c2;
    for (int o = 32; o; o >>= 1) ss += __shfl_xor(ss, o);
    __syncthreads();
    if (lane == 0) red[wid] = ss;
    __syncthreads();
    float var = (red[0] + red[1] + red[2] + red[3]) * (1.0f / 768.0f);
    float sd = var + EPSF;
    float scale = 1.0f / (sd * sd);

    h16* xr = xn + (size_t)row * H_;
    xr[t] = (h16)(c0 * scale); xr[t + 256] = (h16)(c1 * scale); xr[t + 512] = (h16)(c2 * scale);
}

// ============ kernel C: fused pair GEMM (r6 v8 structure; v9 = +nontemporal stores) ============
// out[head, gp, m] = tanh( (xn[b,j]*gc[b,i] + bc[b,i]) @ W[:, cg] + biasc[cg] )
// 64x128 block tile, BK=32, 32x32x16 MFMA, 6 blocks/CU, grid (3,1032).
// r8 post-mortem: all pipes <=25%, six structural rewrites flat -> suspect
// L2 WRITE-ALLOCATE POLLUTION: 101 MB output streams through the 32 MB L2
// ~3x per dispatch, evicting the A rows (re-read by 3 nb-blocks) and B
// tiles between uses.  Fix: nontemporal stores keep the output out of L2.
__global__ __launch_bounds__(256, 6) void k_pair_gemm(
    const h16* __restrict__ Xn, const h16* __restrict__ Gcb, const h16* __restrict__ Bcb,
    const h16* __restrict__ Wpk, const float* __restrict__ biasc,
    float* __restrict__ out)
{
    __shared__ h16 Ash[2][4 * 64 * 8];    // 4 KB per buf
    __shared__ h16 Bsh[2][4 * 128 * 8];   // 8 KB per buf

    const int t = threadIdx.x;
    const int nb = blockIdx.x;            // 0..2 -> cols nb*128 (fast dim)
    const int row0 = blockIdx.y * 64;

    // ---- per-thread staging-row decode (row r_s, k-octet c4) ----
    const int r_s = t >> 2, c4 = t & 3;
    int gp = row0 + r_s;
    int b = gp / P_;
    int p = gp - b * P_;
    int i = (int)((257.0f - sqrtf(66049.0f - 8.0f * (float)p)) * 0.5f);
    if (i < 0) i = 0; if (i > 127) i = 127;
    while (i > 0 && (i * (257 - i)) / 2 > p) --i;
    while (((i + 1) * (256 - i)) / 2 <= p) ++i;
    int j = i + (p - (i * (257 - i)) / 2);

    const h16* xp  = Xn  + (size_t)(b * 128 + j) * H_ + c4 * 8;
    const h16* gp_ = Gcb + (size_t)(b * 128 + i) * H_ + c4 * 8;
    const h16* bp_ = Bcb + (size_t)(b * 128 + i) * H_ + c4 * 8;
    const int aw = (c4 * 64 + r_s) * 8;

    // B DMA: prepacked tile for (nb,kt) is 4096 h16 contiguous, slot order
    const h16* wtile = Wpk + (size_t)nb * 24 * 4096;
    const int wud = t & ~63;              // wave-uniform slot base

    const int lane = t & 63, wid = t >> 6;
    const int wm0 = (wid >> 1) * 32, wn0 = (wid & 1) * 64;
    const int l31 = lane & 31, hi = lane >> 5;

    // ---------- prologue: stage kt=0 into buffer 0 ----------
#pragma unroll
    for (int c = 0; c < 2; ++c)
        gl_lds16(wtile + (size_t)(c * 256 + t) * 8, &Bsh[0][(c * 256 + wud) * 8]);
    {
        uint4 xa = *(const uint4*)xp;
        uint4 ga = *(const uint4*)gp_;
        uint4 ba = *(const uint4*)bp_;
        uint4 f;
        f.x = fuse2(xa.x, ga.x, ba.x); f.y = fuse2(xa.y, ga.y, ba.y);
        f.z = fuse2(xa.z, ga.z, ba.z); f.w = fuse2(xa.w, ga.w, ba.w);
        *(uint4*)&Ash[0][aw] = f;
    }
    __syncthreads();

    f32x16 acc[2] = {};
#pragma unroll 2
    for (int kt = 0; kt < 24; ++kt) {
        const int buf = kt & 1, nbf = buf ^ 1;
        uint4 xa, ga, ba;
        if (kt < 23) {
            // next-B DMA first (longest latency), then next-A loads
            const h16* wnext = wtile + (size_t)(kt + 1) * 4096;
#pragma unroll
            for (int c = 0; c < 2; ++c)
                gl_lds16(wnext + (size_t)(c * 256 + t) * 8, &Bsh[nbf][(c * 256 + wud) * 8]);
            const int k0 = (kt + 1) * 32;
            xa = *(const uint4*)(xp + k0);
            ga = *(const uint4*)(gp_ + k0);
            ba = *(const uint4*)(bp_ + k0);
        }

#pragma unroll
        for (int ks = 0; ks < 2; ++ks) {
            const int ch0 = ks * 2;           // k-window ks*16 -> chunks ch0, ch0+1
            ffrag af, bf[2];
            af = *reinterpret_cast<const ffrag*>(
                &Ash[buf][((ch0 + hi) * 64 + wm0 + l31) * 8]);
#pragma unroll
            for (int ni = 0; ni < 2; ++ni)
                bf[ni] = *reinterpret_cast<const ffrag*>(
                    &Bsh[buf][((ch0 + hi) * 128 + wn0 + ni * 32 + l31) * 8]);
#pragma unroll
            for (int ni = 0; ni < 2; ++ni)
                acc[ni] = __builtin_amdgcn_mfma_f32_32x32x16_f16(af, bf[ni], acc[ni], 0, 0, 0);
        }

        if (kt < 23) {
            uint4 f;
            f.x = fuse2(xa.x, ga.x, ba.x); f.y = fuse2(xa.y, ga.y, ba.y);
            f.z = fuse2(xa.z, ga.z, ba.z); f.w = fuse2(xa.w, ga.w, ba.w);
            *(uint4*)&Ash[nbf][aw] = f;
        }
        __syncthreads();
    }

    // epilogue: bias + tanh + NONTEMPORAL store (head == nb, m == col, BN=128)
    // C/D 32x32: col = lane&31, row = (reg&3) + 8*(reg>>2) + 4*(lane>>5)  [m74/m101]
#pragma unroll
    for (int ni = 0; ni < 2; ++ni) {
        int c = wn0 + ni * 32 + l31;
        float bv = biasc[nb * 128 + c];
#pragma unroll
        for (int reg = 0; reg < 16; ++reg) {
            int rg = wm0 + (reg & 3) + 8 * (reg >> 2) + 4 * hi;
            __builtin_nontemporal_store(fast_tanh(acc[ni][reg] + bv),
                &out[((size_t)nb * BP_ + row0 + rg) * M_ + c]);
        }
    }
}

extern "C" void kernel_launch(void* const* d_in, const int* in_sizes, int n_in,
                              void* d_out, int out_size, void* d_ws, size_t ws_size,
                              hipStream_t stream)
{
    const float* seq     = (const float*)d_in[0];
    const float* gamma   = (const float*)d_in[1];
    const float* beta    = (const float*)d_in[2];
    const float* w_beta  = (const float*)d_in[3];
    const float* w_gamma = (const float*)d_in[4];
    const float* w_ent   = (const float*)d_in[5];
    const float* b_ent   = (const float*)d_in[6];
    const float* w_head  = (const float*)d_in[7];
    const float* b_head  = (const float*)d_in[8];
    const float* w_tail  = (const float*)d_in[9];
    const float* b_tail  = (const float*)d_in[10];
    float* out = (float*)d_out;

    // workspace layout (all 16B-aligned)
    char* ws = (char*)d_ws;
    h16* xn    = (h16*)ws; ws += (size_t)1024 * 768 * 2;  // normalized rows, f16
    h16* wpk   = (h16*)ws; ws += (size_t)294912 * 2;      // pre-packed B tiles [nb][kt][ch][128][8]
    h16* gc    = (h16*)ws; ws += (size_t)1024 * 768 * 2;  // gamma_c f16
    h16* bc    = (h16*)ws; ws += (size_t)1024 * 768 * 2;  // beta_c  f16
    float* biasc = (float*)ws; ws += 384 * 4;             // [ent|head|tail] bias

    hipLaunchKernelGGL(k_pre, dim3(NORM0 + 1024), dim3(256), 0, stream,
                       seq, w_gamma, w_beta, w_ent, w_head, w_tail,
                       gamma, beta, b_ent, b_head, b_tail,
                       wpk, biasc, xn, gc, bc);
    hipLaunchKernelGGL(k_pair_gemm, dim3(3, 1032), dim3(256), 0, stream,
                       xn, gc, bc, wpk, biasc, out);
}

// Round 10
// 200.801 us; speedup vs baseline: 1.0945x; 1.0074x over previous
//
#include <hip/hip_runtime.h>
#include <hip/hip_bf16.h>
#include <hip/hip_fp16.h>
#include <math.h>

// Problem constants (B,S,H,M) = (8,128,768,128)
#define B_   8
#define S_   128
#define H_   768
#define M_   128
#define P_   8256      // S*(S+1)/2 pairs per batch
#define BP_  66048     // B_ * P_
#define EPSF 1e-12f

typedef unsigned short u16;
typedef unsigned int   u32;
typedef _Float16 h16;
typedef _Float16 ffrag __attribute__((ext_vector_type(8)));   // 8 f16 = 4 VGPR
typedef float    f32x16 __attribute__((ext_vector_type(16))); // 32x32 MFMA acc

// packed f16 fma: one v_pk_fma_f16 for two lanes
__device__ __forceinline__ u32 fuse2(u32 x, u32 g, u32 b) {
    __half2 r = __hfma2(__builtin_bit_cast(__half2, x),
                        __builtin_bit_cast(__half2, g),
                        __builtin_bit_cast(__half2, b));
    return __builtin_bit_cast(u32, r);
}
// tanh(x) = 1 - 2/(e^{2x}+1): exp + rcp + fma, branch/copysign-free,
// correct at +-inf (rcp(inf)=0 -> 1; exp(-inf)=0 -> -1)
__device__ __forceinline__ float fast_tanh(float v) {
    float t = __expf(v + v);
    float r = __builtin_amdgcn_rcpf(t + 1.0f);
    return fmaf(-2.0f, r, 1.0f);
}
// async global->LDS 16B per lane; lds dst must be the wave-uniform base
__device__ __forceinline__ void gl_lds16(const h16* g, h16* l) {
    __builtin_amdgcn_global_load_lds(
        (const __attribute__((address_space(1))) u32*)g,
        (__attribute__((address_space(3))) u32*)l, 16, 0, 0);
}
// 8 f32 -> 8 f16 packed as uint4
__device__ __forceinline__ uint4 cvt8(float4 a, float4 b) {
    h16 v[8];
    v[0] = (h16)a.x; v[1] = (h16)a.y; v[2] = (h16)a.z; v[3] = (h16)a.w;
    v[4] = (h16)b.x; v[5] = (h16)b.y; v[6] = (h16)b.z; v[7] = (h16)b.w;
    return *reinterpret_cast<uint4*>(v);
}

// ============ kernel PRE: cond GEMM + wpk prepack + biasc + normalize ============
// One dispatch, disjoint block ranges (r8).  24 KB smem union -> 6 blocks/CU.
//   [0,768):     cond GEMM (f32-staged, 64x32 tiles, BK=64) -> gc/bc
//   [768,792):   wpk prepack via LDS-staged transpose, 1 block per kt,
//                two passes of [3][16][128] f32 (24 KB)
//   [792,794):   biasc (384 f32)
//   [794,1818):  row normalize; xn = (x-mean)/(var+eps)^2
#define CONDB 768
#define WPK0  768
#define BIAS0 792
#define NORM0 794
__global__ __launch_bounds__(256) void k_pre(
    const float* __restrict__ seq,
    const float* __restrict__ wg, const float* __restrict__ wb,
    const float* __restrict__ we, const float* __restrict__ wh,
    const float* __restrict__ wt,
    const float* __restrict__ gamma, const float* __restrict__ beta,
    const float* __restrict__ be, const float* __restrict__ bh,
    const float* __restrict__ bt,
    h16* __restrict__ wpk, float* __restrict__ biasc,
    h16* __restrict__ xn, h16* __restrict__ Gc, h16* __restrict__ Bc)
{
    __shared__ __align__(16) char smem[24576];   // union: cond 13.8KB | wpk 24KB | norm 16B
    const int bx = blockIdx.x;
    const int t = threadIdx.x;

    if (bx < CONDB) {   // ================= cond GEMM =================
        h16* Ash = (h16*)smem;                 // [64*72]
        h16* Bsh = (h16*)smem + 64 * 72;       // [32*72]
        const int rbx = bx & 15, by = bx >> 4;
        const int row0 = rbx * 64;
        const bool isg = (by < 24);
        const int nc0 = (isg ? by : by - 24) * 32;
        const float* wsrc = isg ? wg : wb;

        // A stage: 64 rows x 64 k f32, thread r=t>>2 covers 16 floats at q*16
        const int r = t >> 2, q = t & 3;
        const float* ap = seq + (size_t)(row0 + r) * H_ + q * 16;
        h16* asto = &Ash[r * 72 + q * 16];
        // B stage: 32 rows x 64 k f32, thread rb=t>>3 covers 8 floats at qb*8
        const int rb = t >> 3, qb = t & 7;
        const float* wp = wsrc + (size_t)(nc0 + rb) * H_ + qb * 8;
        h16* bsto = &Bsh[rb * 72 + qb * 8];

        const int lane = t & 63, wid = t >> 6;
        const int wm0 = (wid >> 1) * 32, wn0 = (wid & 1) * 16;
        const int l15 = lane & 15, quad = lane >> 4, q8 = quad * 8;

        typedef float f32x4 __attribute__((ext_vector_type(4)));
        f32x4 acc[2] = {};
        for (int kt = 0; kt < 12; ++kt) {
            const int k0 = kt * 64;
            float4 a0 = *(const float4*)(ap + k0);      float4 a1 = *(const float4*)(ap + k0 + 4);
            float4 a2 = *(const float4*)(ap + k0 + 8);  float4 a3 = *(const float4*)(ap + k0 + 12);
            float4 w0 = *(const float4*)(wp + k0);      float4 w1 = *(const float4*)(wp + k0 + 4);
            *(uint4*)asto = cvt8(a0, a1); *(uint4*)(asto + 8) = cvt8(a2, a3);
            *(uint4*)bsto = cvt8(w0, w1);
            __syncthreads();
#pragma unroll
            for (int ks = 0; ks < 64; ks += 32) {
                ffrag af[2], bf;
#pragma unroll
                for (int mi = 0; mi < 2; ++mi)
                    af[mi] = *reinterpret_cast<const ffrag*>(&Ash[(wm0 + mi * 16 + l15) * 72 + ks + q8]);
                bf = *reinterpret_cast<const ffrag*>(&Bsh[(wn0 + l15) * 72 + ks + q8]);
#pragma unroll
                for (int mi = 0; mi < 2; ++mi)
                    acc[mi] = __builtin_amdgcn_mfma_f32_16x16x32_f16(af[mi], bf, acc[mi], 0, 0, 0);
            }
            __syncthreads();
        }

        const float* bias = isg ? gamma : beta;
        h16* outp = isg ? Gc : Bc;
#pragma unroll
        for (int mi = 0; mi < 2; ++mi) {
            int c = wn0 + l15;
            float bv = bias[nc0 + c];
#pragma unroll
            for (int reg = 0; reg < 4; ++reg) {
                int rg = wm0 + mi * 16 + quad * 4 + reg;   // C/D: col=lane&15, row=quad*4+reg (m89)
                outp[(size_t)(row0 + rg) * H_ + nc0 + c] = (h16)(acc[mi][reg] + bv);
            }
        }
        return;
    }

    if (bx < BIAS0) {   // ================= wpk prepack (1 block per kt, 2 passes) =================
        const int kt = bx - WPK0;
        float* stage = (float*)smem;           // [3][16][128] f32 = 24 KB
#pragma unroll
        for (int pass = 0; pass < 2; ++pass) {
            if (pass) __syncthreads();         // protect stage overwrite
            // stage: coalesced float4 reads, k-rows kt*32+pass*16 .. +16
            int f = t;                         // float4 granule index [0,1536)
#pragma unroll
            for (int k = 0; k < 6; ++k, f += 256) {
                int head = f >> 9, rem = f & 511;
                int r = rem >> 5, m4 = rem & 31;
                const float* src = (head == 0) ? we : (head == 1 ? wh : wt);
                *(float4*)(stage + (size_t)(head * 16 + r) * 128 + m4 * 4) =
                    *(const float4*)(src + (size_t)(kt * 32 + pass * 16 + r) * 128 + m4 * 4);
            }
            __syncthreads();
            // emit: wpk[nb][kt][ch][nl][e], ch = pass*2 + chl; coalesced uint4
#pragma unroll
            for (int e2 = 0; e2 < 3; ++e2) {
                int s = t + 256 * e2;          // [0,768)
                int nbw = s >> 8, rem = s & 255;
                int chl = rem >> 7, nl = rem & 127;
                h16 v[8];
#pragma unroll
                for (int e = 0; e < 8; ++e)
                    v[e] = (h16)stage[(size_t)(nbw * 16 + chl * 8 + e) * 128 + nl];
                *(uint4*)(wpk + (size_t)nbw * 98304 + kt * 4096 +
                          ((pass * 2 + chl) * 128 + nl) * 8) = *(uint4*)v;
            }
            f = t;  // silence unused warnings
        }
        return;
    }

    if (bx < NORM0) {   // ================= biasc =================
        int n = (bx - BIAS0) * 256 + t;
        if (n < 384)
            biasc[n] = (n < 128) ? be[n] : (n < 256 ? bh[n - 128] : bt[n - 256]);
        return;
    }

    // ================= normalize =================
    float* red = (float*)smem;
    const int row = bx - NORM0;
    const int lane = t & 63, wid = t >> 6;
    const float* x = seq + (size_t)row * H_;
    float x0 = x[t], x1 = x[t + 256], x2 = x[t + 512];

    float s = x0 + x1 + x2;
    for (int o = 32; o; o >>= 1) s += __shfl_xor(s, o);
    if (lane == 0) red[wid] = s;
    __syncthreads();
    float mean = (red[0] + red[1] + red[2] + red[3]) * (1.0f / 768.0f);

    float c0 = x0 - mean, c1 = x1 - mean, c2 = x2 - mean;
    float ss = c0 * c0 + c1 * c1 + c2 * c2;
    for (int o = 32; o; o >>= 1) ss += __shfl_xor(ss, o);
    __syncthreads();
    if (lane == 0) red[wid] = ss;
    __syncthreads();
    float var = (red[0] + red[1] + red[2] + red[3]) * (1.0f / 768.0f);
    float sd = var + EPSF;
    float scale = 1.0f / (sd * sd);

    h16* xr = xn + (size_t)row * H_;
    xr[t] = (h16)(c0 * scale); xr[t + 256] = (h16)(c1 * scale); xr[t + 512] = (h16)(c2 * scale);
}

// ============ kernel C: fused pair GEMM (r6 v8 + A-LDS XOR swizzle) ============
// out[head, gp, m] = tanh( (xn[b,j]*gc[b,i] + bc[b,i]) @ W[:, cg] + biasc[cg] )
// 64x128 block tile, BK=32, 32x32x16 MFMA, 6 blocks/CU, grid (3,1032).
// r9 post-mortem: located the 7.1M bank conflicts — the A ds_write:
// thread t writes slot c4*64+r_s; lanes 0-3 (c4=0..3, same r_s) hit byte
// offsets {0,1024,2048,3072} = same bank-quad -> 4-way conflict EVERY stage
// write.  Fix (T2): XOR the chunk id into slot bits 1-2:
//   phys_slot = s ^ (ch<<1)       (16-B slot units)
// write lanes 0-7 now cover 8 distinct bank-quads; af reads stay canonical
// consecutive-16B (XOR constant per instr).  Swizzle applied on BOTH the
// reg-staged write and the ds_read (rule #21).  B path untouched (gl_lds
// linear dst, conflict-free reads).
__global__ __launch_bounds__(256, 6) void k_pair_gemm(
    const h16* __restrict__ Xn, const h16* __restrict__ Gcb, const h16* __restrict__ Bcb,
    const h16* __restrict__ Wpk, const float* __restrict__ biasc,
    float* __restrict__ out)
{
    __shared__ h16 Ash[2][4 * 64 * 8];    // 4 KB per buf
    __shared__ h16 Bsh[2][4 * 128 * 8];   // 8 KB per buf

    const int t = threadIdx.x;
    const int nb = blockIdx.x;            // 0..2 -> cols nb*128 (fast dim)
    const int row0 = blockIdx.y * 64;

    // ---- per-thread staging-row decode (row r_s, k-octet c4) ----
    const int r_s = t >> 2, c4 = t & 3;
    int gp = row0 + r_s;
    int b = gp / P_;
    int p = gp - b * P_;
    int i = (int)((257.0f - sqrtf(66049.0f - 8.0f * (float)p)) * 0.5f);
    if (i < 0) i = 0; if (i > 127) i = 127;
    while (i > 0 && (i * (257 - i)) / 2 > p) --i;
    while (((i + 1) * (256 - i)) / 2 <= p) ++i;
    int j = i + (p - (i * (257 - i)) / 2);

    const h16* xp  = Xn  + (size_t)(b * 128 + j) * H_ + c4 * 8;
    const h16* gp_ = Gcb + (size_t)(b * 128 + i) * H_ + c4 * 8;
    const h16* bp_ = Bcb + (size_t)(b * 128 + i) * H_ + c4 * 8;
    // swizzled A slot: s = c4*64 + r_s ; phys = (s ^ (c4<<1)) * 8 h16
    const int aw = ((c4 * 64 + r_s) ^ (c4 << 1)) * 8;

    // B DMA: prepacked tile for (nb,kt) is 4096 h16 contiguous, slot order
    const h16* wtile = Wpk + (size_t)nb * 24 * 4096;
    const int wud = t & ~63;              // wave-uniform slot base

    const int lane = t & 63, wid = t >> 6;
    const int wm0 = (wid >> 1) * 32, wn0 = (wid & 1) * 64;
    const int l31 = lane & 31, hi = lane >> 5;

    // ---------- prologue: stage kt=0 into buffer 0 ----------
#pragma unroll
    for (int c = 0; c < 2; ++c)
        gl_lds16(wtile + (size_t)(c * 256 + t) * 8, &Bsh[0][(c * 256 + wud) * 8]);
    {
        uint4 xa = *(const uint4*)xp;
        uint4 ga = *(const uint4*)gp_;
        uint4 ba = *(const uint4*)bp_;
        uint4 f;
        f.x = fuse2(xa.x, ga.x, ba.x); f.y = fuse2(xa.y, ga.y, ba.y);
        f.z = fuse2(xa.z, ga.z, ba.z); f.w = fuse2(xa.w, ga.w, ba.w);
        *(uint4*)&Ash[0][aw] = f;
    }
    __syncthreads();

    f32x16 acc[2] = {};
#pragma unroll 2
    for (int kt = 0; kt < 24; ++kt) {
        const int buf = kt & 1, nbf = buf ^ 1;
        uint4 xa, ga, ba;
        if (kt < 23) {
            // next-B DMA first (longest latency), then next-A loads
            const h16* wnext = wtile + (size_t)(kt + 1) * 4096;
#pragma unroll
            for (int c = 0; c < 2; ++c)
                gl_lds16(wnext + (size_t)(c * 256 + t) * 8, &Bsh[nbf][(c * 256 + wud) * 8]);
            const int k0 = (kt + 1) * 32;
            xa = *(const uint4*)(xp + k0);
            ga = *(const uint4*)(gp_ + k0);
            ba = *(const uint4*)(bp_ + k0);
        }

#pragma unroll
        for (int ks = 0; ks < 2; ++ks) {
            const int ch0 = ks * 2;           // k-window ks*16 -> chunks ch0, ch0+1
            const int ch = ch0 + hi;
            ffrag af, bf[2];
            af = *reinterpret_cast<const ffrag*>(
                &Ash[buf][(((ch * 64 + wm0 + l31) ^ (ch << 1))) * 8]);
#pragma unroll
            for (int ni = 0; ni < 2; ++ni)
                bf[ni] = *reinterpret_cast<const ffrag*>(
                    &Bsh[buf][((ch) * 128 + wn0 + ni * 32 + l31) * 8]);
#pragma unroll
            for (int ni = 0; ni < 2; ++ni)
                acc[ni] = __builtin_amdgcn_mfma_f32_32x32x16_f16(af, bf[ni], acc[ni], 0, 0, 0);
        }

        if (kt < 23) {
            uint4 f;
            f.x = fuse2(xa.x, ga.x, ba.x); f.y = fuse2(xa.y, ga.y, ba.y);
            f.z = fuse2(xa.z, ga.z, ba.z); f.w = fuse2(xa.w, ga.w, ba.w);
            *(uint4*)&Ash[nbf][aw] = f;
        }
        __syncthreads();
    }

    // epilogue: bias + tanh + NONTEMPORAL store (head == nb, m == col, BN=128)
    // C/D 32x32: col = lane&31, row = (reg&3) + 8*(reg>>2) + 4*(lane>>5)  [m74/m101]
#pragma unroll
    for (int ni = 0; ni < 2; ++ni) {
        int c = wn0 + ni * 32 + l31;
        float bv = biasc[nb * 128 + c];
#pragma unroll
        for (int reg = 0; reg < 16; ++reg) {
            int rg = wm0 + (reg & 3) + 8 * (reg >> 2) + 4 * hi;
            __builtin_nontemporal_store(fast_tanh(acc[ni][reg] + bv),
                &out[((size_t)nb * BP_ + row0 + rg) * M_ + c]);
        }
    }
}

extern "C" void kernel_launch(void* const* d_in, const int* in_sizes, int n_in,
                              void* d_out, int out_size, void* d_ws, size_t ws_size,
                              hipStream_t stream)
{
    const float* seq     = (const float*)d_in[0];
    const float* gamma   = (const float*)d_in[1];
    const float* beta    = (const float*)d_in[2];
    const float* w_beta  = (const float*)d_in[3];
    const float* w_gamma = (const float*)d_in[4];
    const float* w_ent   = (const float*)d_in[5];
    const float* b_ent   = (const float*)d_in[6];
    const float* w_head  = (const float*)d_in[7];
    const float* b_head  = (const float*)d_in[8];
    const float* w_tail  = (const float*)d_in[9];
    const float* b_tail  = (const float*)d_in[10];
    float* out = (float*)d_out;

    // workspace layout (all 16B-aligned)
    char* ws = (char*)d_ws;
    h16* xn    = (h16*)ws; ws += (size_t)1024 * 768 * 2;  // normalized rows, f16
    h16* wpk   = (h16*)ws; ws += (size_t)294912 * 2;      // pre-packed B tiles [nb][kt][ch][128][8]
    h16* gc    = (h16*)ws; ws += (size_t)1024 * 768 * 2;  // gamma_c f16
    h16* bc    = (h16*)ws; ws += (size_t)1024 * 768 * 2;  // beta_c  f16
    float* biasc = (float*)ws; ws += 384 * 4;             // [ent|head|tail] bias

    hipLaunchKernelGGL(k_pre, dim3(NORM0 + 1024), dim3(256), 0, stream,
                       seq, w_gamma, w_beta, w_ent, w_head, w_tail,
                       gamma, beta, b_ent, b_head, b_tail,
                       wpk, biasc, xn, gc, bc);
    hipLaunchKernelGGL(k_pair_gemm, dim3(3, 1032), dim3(256), 0, stream,
                       xn, gc, bc, wpk, biasc, out);
}